// Round 3
// baseline (3474.666 us; speedup 1.0000x reference)
//
#include <hip/hip_runtime.h>
#include <math.h>

// Problem constants
#define NW    32768   // B*W = 512*64 windows
#define G     8       // windows per block
#define NBLK  (NW / G)
#define NT    256

// Dims
#define ND    172     // NODE_DIM = EDGE_DIM = TIME_DIM
#define EVD   347     // EVENT_DIM
#define HID   64
#define D2    128
#define MLPD  76

// LDS overlays (float offsets). Liveness:
//   O_EV  : ev[24][172] (phase1 out) -> u0[24][172] in-place (2a) ; [0..1536) reused as H1 (2b-p1)
//   O_EF  : ef[8][348] (phase0/1, three passes) -> u1[24][172] (2a)
//   O_H0  : h0[24][64] (2b-p0)
//   O_H1  : h1[24][64] over dead u0 rows
//   O_FEAT: feat[8][3][128] over dead u0/u1
//   O_SC  : phase-3 scratch (2816) over dead u1
#define O_EV   0       // 4128
#define O_EF   4128    // 4176 region (ef uses 2784; u1 uses 4128)
#define O_H0   8304    // 1536
#define O_H1   0       // 1536
#define O_FEAT 1536    // 3072  [1536..4608)
#define O_SC   4608    // 2816  [4608..7424)
#define LDS_F  9840    // 39360 B -> 4 blocks/CU (LDS-limited)

__global__ __launch_bounds__(256) void tempme_fused(
    const int*   __restrict__ node_idx,      // (NW, 6)
    const int*   __restrict__ edge_idx,      // (NW, 3)
    const int*   __restrict__ cat_feat,      // (NW, 1)
    const float* __restrict__ t_records,     // (NW, 3)
    const float* __restrict__ edge_identify, // (NW, 3, 3)
    const float* __restrict__ node_embed,    // (10000, 172)
    const float* __restrict__ edge_embed,    // (200000, 172)
    const float* __restrict__ basis_freq,    // (172,)
    const float* __restrict__ phase,         // (172,)
    const float* __restrict__ lin_event_w,   // (172, 347)
    const float* __restrict__ lin_event_b,   // (172,)
    const float* __restrict__ gcn_w1,        // (64, 172)
    const float* __restrict__ gcn_b1,        // (64,)
    const float* __restrict__ gcn_w2,        // (64, 64)
    const float* __restrict__ gcn_b2,        // (64,)
    const float* __restrict__ att_w1_w,      // (128, 128)
    const float* __restrict__ att_w1_b,      // (128,)
    const float* __restrict__ att_w2_w,      // (128, 128)
    const float* __restrict__ att_w2_b,      // (128,)
    const float* __restrict__ att_m1_w,      // (64, 128)
    const float* __restrict__ att_m1_b,      // (64,)
    const float* __restrict__ att_m2_w,      // (64, 64)
    const float* __restrict__ att_m2_b,      // (64,)
    const float* __restrict__ mlp_w1,        // (76, 76)
    const float* __restrict__ mlp_b1,        // (76,)
    const float* __restrict__ mlp_w2,        // (64, 76)
    const float* __restrict__ mlp_b2,        // (64,)
    const float* __restrict__ mlp_w3,        // (1, 64)
    const float* __restrict__ mlp_b3,        // (1,)
    float*       __restrict__ out)           // (NW,)
{
  __shared__ __align__(16) float lds[LDS_F];
  const int tid = threadIdx.x;
  const int bw0 = blockIdx.x * G;

  // ============ phases 0+1: event features + event linear, 3 passes of 8 rows ============
  // acc[8] + 8 in-flight float4 ~= 45 VGPRs: fits even a 64-VGPR budget (no spill at any
  // allocator occupancy target -- R2's launch_bounds min-waves hint caused 64-reg spills).
  for (int p = 0; p < 3; ++p) {
    // phase 0: build ef[lr][0..347) for rows r = 8p..8p+7
    for (int lr = 0; lr < 8; ++lr) {
      const int r   = p * 8 + lr;
      const int g   = r / 3;
      const int l   = r - 3 * g;
      const int bw  = bw0 + g;
      const int rid = bw * 3 + l;
      const int e   = edge_idx[rid];
      const float dt = t_records[bw * 3 + 2] - t_records[rid];
      const float* erow = edge_embed + (long)e * ND;
      for (int k = tid; k < EVD; k += NT) {
        float v;
        if (k < ND) {
          v = erow[k];
        } else if (k < ND + 3) {
          v = edge_identify[rid * 3 + (k - ND)];
        } else {
          const int d = k - (ND + 3);
          v = cosf(fmaf(dt, basis_freq[d], phase[d]));
        }
        lds[O_EF + lr * 348 + k] = v;
      }
    }
    __syncthreads();

    // phase 1: ev[8p+i][tid] = lin_event_w[tid] . ef[i] + b[tid]
    if (tid < ND) {
      float acc[8];
#pragma unroll
      for (int i = 0; i < 8; ++i) acc[i] = 0.f;
      const float* wrow = lin_event_w + tid * EVD;
      for (int k = 0; k < 344; k += 4) {
        const float w0 = wrow[k], w1 = wrow[k + 1], w2 = wrow[k + 2], w3 = wrow[k + 3];
#pragma unroll
        for (int i = 0; i < 8; ++i) {
          const float4 e4 = *(const float4*)&lds[O_EF + i * 348 + k];  // wave broadcast
          acc[i] = fmaf(w0, e4.x, fmaf(w1, e4.y, fmaf(w2, e4.z, fmaf(w3, e4.w, acc[i]))));
        }
      }
      for (int k = 344; k < EVD; ++k) {
        const float w = wrow[k];
#pragma unroll
        for (int i = 0; i < 8; ++i) acc[i] = fmaf(w, lds[O_EF + i * 348 + k], acc[i]);
      }
      const float bo = lin_event_b[tid];
#pragma unroll
      for (int i = 0; i < 8; ++i) lds[O_EV + (p * 8 + i) * ND + tid] = acc[i] + bo;
    }
    __syncthreads();
  }

  // ============ phase 2a: u0 = s + relu(t+e) (in-place over ev); u1 = t + relu(s+e) ============
  for (int r = 0; r < 24; ++r) {
    const int g  = r / 3;
    const int l  = r - 3 * g;
    const int bw = bw0 + g;
    const int si = node_idx[bw * 6 + 2 * l];
    const int ti = node_idx[bw * 6 + 2 * l + 1];
    if (tid < ND) {
      const float e = lds[O_EV + r * ND + tid];
      const float s = node_embed[(long)si * ND + tid];
      const float t = node_embed[(long)ti * ND + tid];
      lds[O_EV + r * ND + tid] = s + fmaxf(t + e, 0.f);  // u0
      lds[O_EF + r * ND + tid] = t + fmaxf(s + e, 0.f);  // u1
    }
  }
  __syncthreads();

  // ============ phase 2b: h_d[r][j] = relu(gcn_w1[j] . u_d[r] + b1[j]), d=0,1 ============
  {
    const int j  = tid & 63;
    const int rg = tid >> 6;  // 4 groups x 6 rows
    for (int d = 0; d < 2; ++d) {
      const float* U = &lds[d == 0 ? O_EV : O_EF];
      float acc[6];
#pragma unroll
      for (int i = 0; i < 6; ++i) acc[i] = 0.f;
      const float* wrow = gcn_w1 + j * ND;  // 688B rows, 16B aligned
      for (int k = 0; k < ND; k += 4) {
        const float4 w4 = *(const float4*)(wrow + k);
#pragma unroll
        for (int i = 0; i < 6; ++i) {
          const float4 u4 = *(const float4*)&U[(rg * 6 + i) * ND + k];
          acc[i] = fmaf(w4.x, u4.x, fmaf(w4.y, u4.y, fmaf(w4.z, u4.z, fmaf(w4.w, u4.w, acc[i]))));
        }
      }
      const float b = gcn_b1[j];
      float* H = &lds[d == 0 ? O_H0 : O_H1];
#pragma unroll
      for (int i = 0; i < 6; ++i) H[(rg * 6 + i) * HID + j] = fmaxf(acc[i] + b, 0.f);
      __syncthreads();  // d=0: u0 reads complete before d=1 overwrites [0..1536) with h1
    }
  }

  // ============ phase 2c: feat[g][l][d*64+j] = gcn_w2[j] . h_d[3g+l] + b2[j] ============
  {
    const int j  = tid & 63;
    const int rg = tid >> 6;
    for (int d = 0; d < 2; ++d) {
      const float* H = &lds[d == 0 ? O_H0 : O_H1];
      float acc[6];
#pragma unroll
      for (int i = 0; i < 6; ++i) acc[i] = 0.f;
      const float* wrow = gcn_w2 + j * HID;
      for (int k = 0; k < HID; k += 4) {
        const float4 w4 = *(const float4*)(wrow + k);
#pragma unroll
        for (int i = 0; i < 6; ++i) {
          const float4 h4 = *(const float4*)&H[(rg * 6 + i) * HID + k];
          acc[i] = fmaf(w4.x, h4.x, fmaf(w4.y, h4.y, fmaf(w4.z, h4.z, fmaf(w4.w, h4.w, acc[i]))));
        }
      }
      const float b = gcn_b2[j];
#pragma unroll
      for (int i = 0; i < 6; ++i) {
        const int r = rg * 6 + i;
        const int g = r / 3;
        const int l = r - 3 * g;
        lds[O_FEAT + g * 384 + l * 128 + d * HID + j] = acc[i] + b;
      }
      // no barrier between d passes: feat slots disjoint from both H regions
    }
  }
  __syncthreads();

  // ============ phase 3: attention + MLP head (all LDS slots wave-private per g) ============
  {
    const int wv   = tid >> 6;
    const int lane = tid & 63;
    float* sc_out = &lds[O_SC];           // 8*128
    float* sc_m1  = &lds[O_SC + 1024];    // 8*64
    float* sc_x   = &lds[O_SC + 1536];    // 8*80
    float* sc_h1  = &lds[O_SC + 2176];    // 8*80
    for (int it = 0; it < 2; ++it) {
      const int g  = wv * 2 + it;
      const int bw = bw0 + g;
      const float* fg = &lds[O_FEAT + g * 384];

      // Wp = att_w1 @ src + b1 ; lane owns d = lane, lane+64
      float p0 = att_w1_b[lane], p1 = att_w1_b[lane + 64];
      {
        const float* r0 = att_w1_w + lane * D2;
        const float* r1 = att_w1_w + (lane + 64) * D2;
        for (int e = 0; e < D2; e += 4) {
          const float4 f4 = *(const float4*)&fg[256 + e];
          const float4 a4 = *(const float4*)(r0 + e);
          const float4 b4 = *(const float4*)(r1 + e);
          p0 = fmaf(a4.x, f4.x, fmaf(a4.y, f4.y, fmaf(a4.z, f4.z, fmaf(a4.w, f4.w, p0))));
          p1 = fmaf(b4.x, f4.x, fmaf(b4.y, f4.y, fmaf(b4.z, f4.z, fmaf(b4.w, f4.w, p1))));
        }
      }
      // Wq[k] = att_w2 @ feat[k] + b2, k = 0,1
      float q00 = att_w2_b[lane], q01 = att_w2_b[lane + 64];
      float q10 = q00, q11 = q01;
      {
        const float* r0 = att_w2_w + lane * D2;
        const float* r1 = att_w2_w + (lane + 64) * D2;
        for (int e = 0; e < D2; e += 4) {
          const float4 a4 = *(const float4*)(r0 + e);
          const float4 b4 = *(const float4*)(r1 + e);
          const float4 f0 = *(const float4*)&fg[e];
          const float4 f1 = *(const float4*)&fg[128 + e];
          q00 = fmaf(a4.x, f0.x, fmaf(a4.y, f0.y, fmaf(a4.z, f0.z, fmaf(a4.w, f0.w, q00))));
          q01 = fmaf(b4.x, f0.x, fmaf(b4.y, f0.y, fmaf(b4.z, f0.z, fmaf(b4.w, f0.w, q01))));
          q10 = fmaf(a4.x, f1.x, fmaf(a4.y, f1.y, fmaf(a4.z, f1.z, fmaf(a4.w, f1.w, q10))));
          q11 = fmaf(b4.x, f1.x, fmaf(b4.y, f1.y, fmaf(b4.z, f1.w, fmaf(b4.w, f1.w, q11))));
        }
      }
      // scores (2 keys) + softmax (wave reductions)
      float s0 = p0 * q00 + p1 * q01;
      float s1 = p0 * q10 + p1 * q11;
#pragma unroll
      for (int off = 32; off >= 1; off >>= 1) {
        s0 += __shfl_xor(s0, off, 64);
        s1 += __shfl_xor(s1, off, 64);
      }
      const float mx = fmaxf(s0, s1);
      const float e0 = expf(s0 - mx), e1 = expf(s1 - mx);
      const float inv = 1.f / (e0 + e1);
      const float a0 = e0 * inv, a1 = e1 * inv;
      // out = src + a0*Wq0 + a1*Wq1  (wave-private slot; same-wave RAW handled by lgkmcnt)
      sc_out[g * 128 + lane]      = fg[256 + lane]      + a0 * q00 + a1 * q10;
      sc_out[g * 128 + 64 + lane] = fg[256 + 64 + lane] + a0 * q01 + a1 * q11;

      // m1 = relu(att_m1 @ out + b)
      float m1 = att_m1_b[lane];
      {
        const float* wr = att_m1_w + lane * D2;
        const float* ob = sc_out + g * 128;
        for (int d = 0; d < D2; d += 4) {
          const float4 w4 = *(const float4*)(wr + d);
          const float4 o4 = *(const float4*)&ob[d];
          m1 = fmaf(w4.x, o4.x, fmaf(w4.y, o4.y, fmaf(w4.z, o4.z, fmaf(w4.w, o4.w, m1))));
        }
      }
      sc_m1[g * 64 + lane] = fmaxf(m1, 0.f);

      // h = att_m2 @ m1 + b
      float hv = att_m2_b[lane];
      {
        const float* wr = att_m2_w + lane * HID;
        const float* mb = sc_m1 + g * 64;
        for (int d = 0; d < HID; d += 4) {
          const float4 w4 = *(const float4*)(wr + d);
          const float4 m4 = *(const float4*)&mb[d];
          hv = fmaf(w4.x, m4.x, fmaf(w4.y, m4.y, fmaf(w4.z, m4.z, fmaf(w4.w, m4.w, hv))));
        }
      }
      // x = concat(h, one_hot(cat,12))
      sc_x[g * 80 + lane] = hv;
      if (lane < 12) {
        const int cat = cat_feat[bw];
        sc_x[g * 80 + 64 + lane] = (cat == lane) ? 1.f : 0.f;
      }

      // h1 = relu(mlp_w1 @ x + b1) : 76 outputs
      const float* xb = sc_x + g * 80;
      {
        float h1a = mlp_b1[lane];
        const float* wr = mlp_w1 + lane * MLPD;
        for (int k = 0; k < MLPD; k += 4) {
          const float4 w4 = *(const float4*)(wr + k);
          const float4 x4 = *(const float4*)&xb[k];
          h1a = fmaf(w4.x, x4.x, fmaf(w4.y, x4.y, fmaf(w4.z, x4.z, fmaf(w4.w, x4.w, h1a))));
        }
        sc_h1[g * 80 + lane] = fmaxf(h1a, 0.f);
        if (lane < 12) {
          float h1b = mlp_b1[64 + lane];
          const float* wr2 = mlp_w1 + (64 + lane) * MLPD;
          for (int k = 0; k < MLPD; k += 4) {
            const float4 w4 = *(const float4*)(wr2 + k);
            const float4 x4 = *(const float4*)&xb[k];
            h1b = fmaf(w4.x, x4.x, fmaf(w4.y, x4.y, fmaf(w4.z, x4.z, fmaf(w4.w, x4.w, h1b))));
          }
          sc_h1[g * 80 + 64 + lane] = fmaxf(h1b, 0.f);
        }
      }

      // h2 = relu(mlp_w2 @ h1 + b2) ; z = mlp_w3 @ h2 + b3 ; sigmoid
      float h2 = mlp_b2[lane];
      {
        const float* wr = mlp_w2 + lane * MLPD;
        const float* hb = sc_h1 + g * 80;
        for (int k = 0; k < MLPD; k += 4) {
          const float4 w4 = *(const float4*)(wr + k);
          const float4 h4 = *(const float4*)&hb[k];
          h2 = fmaf(w4.x, h4.x, fmaf(w4.y, h4.y, fmaf(w4.z, h4.z, fmaf(w4.w, h4.w, h2))));
        }
      }
      h2 = fmaxf(h2, 0.f);
      float zz = mlp_w3[lane] * h2;
#pragma unroll
      for (int off = 32; off >= 1; off >>= 1) zz += __shfl_xor(zz, off, 64);
      if (lane == 0) out[bw] = 1.f / (1.f + expf(-(zz + mlp_b3[0])));
    }
  }
}

extern "C" void kernel_launch(void* const* d_in, const int* in_sizes, int n_in,
                              void* d_out, int out_size, void* d_ws, size_t ws_size,
                              hipStream_t stream) {
  tempme_fused<<<NBLK, NT, 0, stream>>>(
      (const int*)d_in[0],    // node_idx
      (const int*)d_in[1],    // edge_idx
      (const int*)d_in[2],    // cat_feat
      (const float*)d_in[3],  // t_records
      (const float*)d_in[4],  // edge_identify
      // d_in[5] cut_time_l unused by reference
      (const float*)d_in[6],  // node_embed
      (const float*)d_in[7],  // edge_embed
      (const float*)d_in[8],  // basis_freq
      (const float*)d_in[9],  // phase
      (const float*)d_in[10], (const float*)d_in[11],  // lin_event
      (const float*)d_in[12], (const float*)d_in[13],  // gcn1
      (const float*)d_in[14], (const float*)d_in[15],  // gcn2
      (const float*)d_in[16], (const float*)d_in[17],  // att_w1
      (const float*)d_in[18], (const float*)d_in[19],  // att_w2
      (const float*)d_in[20], (const float*)d_in[21],  // att_m1
      (const float*)d_in[22], (const float*)d_in[23],  // att_m2
      (const float*)d_in[24], (const float*)d_in[25],  // mlp1
      (const float*)d_in[26], (const float*)d_in[27],  // mlp2
      (const float*)d_in[28], (const float*)d_in[29],  // mlp3
      (float*)d_out);
}

// Round 4
// 1522.198 us; speedup vs baseline: 2.2827x; 2.2827x over previous
//
#include <hip/hip_runtime.h>
#include <math.h>

// Problem constants
#define NW    32768   // B*W = 512*64 windows
#define G     8       // windows per block
#define NBLK  (NW / G)
#define NT    256

// Dims
#define ND    172     // NODE_DIM = EDGE_DIM = TIME_DIM
#define EVD   347     // EVENT_DIM
#define HID   64
#define D2    128
#define MLPD  76

// LDS overlays (float offsets). Liveness:
//   O_EV  : ev[24][172] (phase1 out) -> u0[24][172] in-place (2a) ; [0..1536) reused as H1 (2b-p1)
//   O_EF  : ef[8][348] (phase0/1, three passes) -> u1[24][172] (2a)
//   O_H0  : h0[24][64] (2b-p0)
//   O_H1  : h1[24][64] over dead u0 rows
//   O_FEAT: feat[8][3][128] over dead u0/u1
//   O_SC  : phase-3 scratch (2816) over dead u1
#define O_EV   0       // 4128
#define O_EF   4128    // 4176 region (ef uses 2784; u1 uses 4128)
#define O_H0   8304    // 1536
#define O_H1   0       // 1536
#define O_FEAT 1536    // 3072  [1536..4608)
#define O_SC   4608    // 2816  [4608..7424)
#define LDS_F  9840    // 39360 B -> 4 blocks/CU (LDS-limited)

// NOTE (R3 post-mortem): full unroll of the 32-trip dot loops made the
// scheduler hoist ALL independent float4 loads -> >256 VGPR demand ->
// ~1.6 GB scratch spill traffic (WRITE_SIZE identical across R1/R3 because
// phase 3 was identical). Every long dot loop below carries `#pragma unroll 2`
// and every structural/multi-pass loop carries `#pragma unroll 1`.

__global__ __launch_bounds__(256) void tempme_fused(
    const int*   __restrict__ node_idx,      // (NW, 6)
    const int*   __restrict__ edge_idx,      // (NW, 3)
    const int*   __restrict__ cat_feat,      // (NW, 1)
    const float* __restrict__ t_records,     // (NW, 3)
    const float* __restrict__ edge_identify, // (NW, 3, 3)
    const float* __restrict__ node_embed,    // (10000, 172)
    const float* __restrict__ edge_embed,    // (200000, 172)
    const float* __restrict__ basis_freq,    // (172,)
    const float* __restrict__ phase,         // (172,)
    const float* __restrict__ lin_event_w,   // (172, 347)
    const float* __restrict__ lin_event_b,   // (172,)
    const float* __restrict__ gcn_w1,        // (64, 172)
    const float* __restrict__ gcn_b1,        // (64,)
    const float* __restrict__ gcn_w2,        // (64, 64)
    const float* __restrict__ gcn_b2,        // (64,)
    const float* __restrict__ att_w1_w,      // (128, 128)
    const float* __restrict__ att_w1_b,      // (128,)
    const float* __restrict__ att_w2_w,      // (128, 128)
    const float* __restrict__ att_w2_b,      // (128,)
    const float* __restrict__ att_m1_w,      // (64, 128)
    const float* __restrict__ att_m1_b,      // (64,)
    const float* __restrict__ att_m2_w,      // (64, 64)
    const float* __restrict__ att_m2_b,      // (64,)
    const float* __restrict__ mlp_w1,        // (76, 76)
    const float* __restrict__ mlp_b1,        // (76,)
    const float* __restrict__ mlp_w2,        // (64, 76)
    const float* __restrict__ mlp_b2,        // (64,)
    const float* __restrict__ mlp_w3,        // (1, 64)
    const float* __restrict__ mlp_b3,        // (1,)
    float*       __restrict__ out)           // (NW,)
{
  __shared__ __align__(16) float lds[LDS_F];
  const int tid = threadIdx.x;
  const int bw0 = blockIdx.x * G;

  // ============ phases 0+1: event features + event linear, 3 passes of 8 rows ============
#pragma unroll 1
  for (int p = 0; p < 3; ++p) {
    // phase 0: build ef[lr][0..347) for rows r = 8p..8p+7
#pragma unroll 1
    for (int lr = 0; lr < 8; ++lr) {
      const int r   = p * 8 + lr;
      const int g   = r / 3;
      const int l   = r - 3 * g;
      const int bw  = bw0 + g;
      const int rid = bw * 3 + l;
      const int e   = edge_idx[rid];
      const float dt = t_records[bw * 3 + 2] - t_records[rid];
      const float* erow = edge_embed + (long)e * ND;
#pragma unroll 1
      for (int k = tid; k < EVD; k += NT) {
        float v;
        if (k < ND) {
          v = erow[k];
        } else if (k < ND + 3) {
          v = edge_identify[rid * 3 + (k - ND)];
        } else {
          const int d = k - (ND + 3);
          // native v_cos_f32 (input in revolutions). |arg| < 1 rad -> |rev| < 0.16,
          // well inside the accurate domain; avoids any libm call/stack frame.
          v = __cosf(fmaf(dt, basis_freq[d], phase[d]));
        }
        lds[O_EF + lr * 348 + k] = v;
      }
    }
    __syncthreads();

    // phase 1: ev[8p+i][tid] = lin_event_w[tid] . ef[i] + b[tid]
    if (tid < ND) {
      float acc[8];
#pragma unroll
      for (int i = 0; i < 8; ++i) acc[i] = 0.f;
      const float* wrow = lin_event_w + tid * EVD;
#pragma unroll 2
      for (int k = 0; k < 344; k += 4) {
        const float w0 = wrow[k], w1 = wrow[k + 1], w2 = wrow[k + 2], w3 = wrow[k + 3];
#pragma unroll
        for (int i = 0; i < 8; ++i) {
          const float4 e4 = *(const float4*)&lds[O_EF + i * 348 + k];  // wave broadcast
          acc[i] = fmaf(w0, e4.x, fmaf(w1, e4.y, fmaf(w2, e4.z, fmaf(w3, e4.w, acc[i]))));
        }
      }
#pragma unroll 1
      for (int k = 344; k < EVD; ++k) {
        const float w = wrow[k];
#pragma unroll
        for (int i = 0; i < 8; ++i) acc[i] = fmaf(w, lds[O_EF + i * 348 + k], acc[i]);
      }
      const float bo = lin_event_b[tid];
#pragma unroll
      for (int i = 0; i < 8; ++i) lds[O_EV + (p * 8 + i) * ND + tid] = acc[i] + bo;
    }
    __syncthreads();
  }

  // ============ phase 2a: u0 = s + relu(t+e) (in-place over ev); u1 = t + relu(s+e) ============
#pragma unroll 1
  for (int r = 0; r < 24; ++r) {
    const int g  = r / 3;
    const int l  = r - 3 * g;
    const int bw = bw0 + g;
    const int si = node_idx[bw * 6 + 2 * l];
    const int ti = node_idx[bw * 6 + 2 * l + 1];
    if (tid < ND) {
      const float e = lds[O_EV + r * ND + tid];
      const float s = node_embed[(long)si * ND + tid];
      const float t = node_embed[(long)ti * ND + tid];
      lds[O_EV + r * ND + tid] = s + fmaxf(t + e, 0.f);  // u0
      lds[O_EF + r * ND + tid] = t + fmaxf(s + e, 0.f);  // u1
    }
  }
  __syncthreads();

  // ============ phase 2b: h_d[r][j] = relu(gcn_w1[j] . u_d[r] + b1[j]), d=0,1 ============
  {
    const int j  = tid & 63;
    const int rg = tid >> 6;  // 4 groups x 6 rows
#pragma unroll 1
    for (int d = 0; d < 2; ++d) {
      const float* U = &lds[d == 0 ? O_EV : O_EF];
      float acc[6];
#pragma unroll
      for (int i = 0; i < 6; ++i) acc[i] = 0.f;
      const float* wrow = gcn_w1 + j * ND;  // 688B rows, 16B aligned
#pragma unroll 2
      for (int k = 0; k < ND; k += 4) {
        const float4 w4 = *(const float4*)(wrow + k);
#pragma unroll
        for (int i = 0; i < 6; ++i) {
          const float4 u4 = *(const float4*)&U[(rg * 6 + i) * ND + k];
          acc[i] = fmaf(w4.x, u4.x, fmaf(w4.y, u4.y, fmaf(w4.z, u4.z, fmaf(w4.w, u4.w, acc[i]))));
        }
      }
      const float b = gcn_b1[j];
      float* H = &lds[d == 0 ? O_H0 : O_H1];
#pragma unroll
      for (int i = 0; i < 6; ++i) H[(rg * 6 + i) * HID + j] = fmaxf(acc[i] + b, 0.f);
      __syncthreads();  // d=0: u0 reads complete before d=1 overwrites [0..1536) with h1
    }
  }

  // ============ phase 2c: feat[g][l][d*64+j] = gcn_w2[j] . h_d[3g+l] + b2[j] ============
  {
    const int j  = tid & 63;
    const int rg = tid >> 6;
#pragma unroll 1
    for (int d = 0; d < 2; ++d) {
      const float* H = &lds[d == 0 ? O_H0 : O_H1];
      float acc[6];
#pragma unroll
      for (int i = 0; i < 6; ++i) acc[i] = 0.f;
      const float* wrow = gcn_w2 + j * HID;
#pragma unroll 2
      for (int k = 0; k < HID; k += 4) {
        const float4 w4 = *(const float4*)(wrow + k);
#pragma unroll
        for (int i = 0; i < 6; ++i) {
          const float4 h4 = *(const float4*)&H[(rg * 6 + i) * HID + k];
          acc[i] = fmaf(w4.x, h4.x, fmaf(w4.y, h4.y, fmaf(w4.z, h4.z, fmaf(w4.w, h4.w, acc[i]))));
        }
      }
      const float b = gcn_b2[j];
#pragma unroll
      for (int i = 0; i < 6; ++i) {
        const int r = rg * 6 + i;
        const int g = r / 3;
        const int l = r - 3 * g;
        lds[O_FEAT + g * 384 + l * 128 + d * HID + j] = acc[i] + b;
      }
      // no barrier between d passes: feat slots disjoint from both H regions
    }
  }
  __syncthreads();

  // ============ phase 3: attention + MLP head (all LDS slots wave-private per g) ============
  {
    const int wv   = tid >> 6;
    const int lane = tid & 63;
    float* sc_out = &lds[O_SC];           // 8*128
    float* sc_m1  = &lds[O_SC + 1024];    // 8*64
    float* sc_x   = &lds[O_SC + 1536];    // 8*80
    float* sc_h1  = &lds[O_SC + 2176];    // 8*80
#pragma unroll 1
    for (int it = 0; it < 2; ++it) {
      const int g  = wv * 2 + it;
      const int bw = bw0 + g;
      const float* fg = &lds[O_FEAT + g * 384];

      // Wp = att_w1 @ src + b1 ; lane owns d = lane, lane+64
      float p0 = att_w1_b[lane], p1 = att_w1_b[lane + 64];
      {
        const float* r0 = att_w1_w + lane * D2;
        const float* r1 = att_w1_w + (lane + 64) * D2;
#pragma unroll 2
        for (int e = 0; e < D2; e += 4) {
          const float4 f4 = *(const float4*)&fg[256 + e];
          const float4 a4 = *(const float4*)(r0 + e);
          const float4 b4 = *(const float4*)(r1 + e);
          p0 = fmaf(a4.x, f4.x, fmaf(a4.y, f4.y, fmaf(a4.z, f4.z, fmaf(a4.w, f4.w, p0))));
          p1 = fmaf(b4.x, f4.x, fmaf(b4.y, f4.y, fmaf(b4.z, f4.z, fmaf(b4.w, f4.w, p1))));
        }
      }
      // Wq[k] = att_w2 @ feat[k] + b2, k = 0,1
      float q00 = att_w2_b[lane], q01 = att_w2_b[lane + 64];
      float q10 = q00, q11 = q01;
      {
        const float* r0 = att_w2_w + lane * D2;
        const float* r1 = att_w2_w + (lane + 64) * D2;
#pragma unroll 2
        for (int e = 0; e < D2; e += 4) {
          const float4 a4 = *(const float4*)(r0 + e);
          const float4 b4 = *(const float4*)(r1 + e);
          const float4 f0 = *(const float4*)&fg[e];
          const float4 f1 = *(const float4*)&fg[128 + e];
          q00 = fmaf(a4.x, f0.x, fmaf(a4.y, f0.y, fmaf(a4.z, f0.z, fmaf(a4.w, f0.w, q00))));
          q01 = fmaf(b4.x, f0.x, fmaf(b4.y, f0.y, fmaf(b4.z, f0.z, fmaf(b4.w, f0.w, q01))));
          q10 = fmaf(a4.x, f1.x, fmaf(a4.y, f1.y, fmaf(a4.z, f1.z, fmaf(a4.w, f1.w, q10))));
          q11 = fmaf(b4.x, f1.x, fmaf(b4.y, f1.y, fmaf(b4.z, f1.z, fmaf(b4.w, f1.w, q11))));  // R3 typo fixed
        }
      }
      // scores (2 keys) + softmax (wave reductions)
      float s0 = p0 * q00 + p1 * q01;
      float s1 = p0 * q10 + p1 * q11;
#pragma unroll
      for (int off = 32; off >= 1; off >>= 1) {
        s0 += __shfl_xor(s0, off, 64);
        s1 += __shfl_xor(s1, off, 64);
      }
      const float mx = fmaxf(s0, s1);
      const float e0 = __expf(s0 - mx), e1 = __expf(s1 - mx);
      const float inv = 1.f / (e0 + e1);
      const float a0 = e0 * inv, a1 = e1 * inv;
      // out = src + a0*Wq0 + a1*Wq1  (wave-private slot; same-wave RAW handled by lgkmcnt)
      sc_out[g * 128 + lane]      = fg[256 + lane]      + a0 * q00 + a1 * q10;
      sc_out[g * 128 + 64 + lane] = fg[256 + 64 + lane] + a0 * q01 + a1 * q11;

      // m1 = relu(att_m1 @ out + b)
      float m1 = att_m1_b[lane];
      {
        const float* wr = att_m1_w + lane * D2;
        const float* ob = sc_out + g * 128;
#pragma unroll 2
        for (int d = 0; d < D2; d += 4) {
          const float4 w4 = *(const float4*)(wr + d);
          const float4 o4 = *(const float4*)&ob[d];
          m1 = fmaf(w4.x, o4.x, fmaf(w4.y, o4.y, fmaf(w4.z, o4.z, fmaf(w4.w, o4.w, m1))));
        }
      }
      sc_m1[g * 64 + lane] = fmaxf(m1, 0.f);

      // h = att_m2 @ m1 + b
      float hv = att_m2_b[lane];
      {
        const float* wr = att_m2_w + lane * HID;
        const float* mb = sc_m1 + g * 64;
#pragma unroll 2
        for (int d = 0; d < HID; d += 4) {
          const float4 w4 = *(const float4*)(wr + d);
          const float4 m4 = *(const float4*)&mb[d];
          hv = fmaf(w4.x, m4.x, fmaf(w4.y, m4.y, fmaf(w4.z, m4.z, fmaf(w4.w, m4.w, hv))));
        }
      }
      // x = concat(h, one_hot(cat,12))
      sc_x[g * 80 + lane] = hv;
      if (lane < 12) {
        const int cat = cat_feat[bw];
        sc_x[g * 80 + 64 + lane] = (cat == lane) ? 1.f : 0.f;
      }

      // h1 = relu(mlp_w1 @ x + b1) : 76 outputs
      const float* xb = sc_x + g * 80;
      {
        float h1a = mlp_b1[lane];
        const float* wr = mlp_w1 + lane * MLPD;
#pragma unroll 2
        for (int k = 0; k < MLPD; k += 4) {
          const float4 w4 = *(const float4*)(wr + k);
          const float4 x4 = *(const float4*)&xb[k];
          h1a = fmaf(w4.x, x4.x, fmaf(w4.y, x4.y, fmaf(w4.z, x4.z, fmaf(w4.w, x4.w, h1a))));
        }
        sc_h1[g * 80 + lane] = fmaxf(h1a, 0.f);
        if (lane < 12) {
          float h1b = mlp_b1[64 + lane];
          const float* wr2 = mlp_w1 + (64 + lane) * MLPD;
#pragma unroll 2
          for (int k = 0; k < MLPD; k += 4) {
            const float4 w4 = *(const float4*)(wr2 + k);
            const float4 x4 = *(const float4*)&xb[k];
            h1b = fmaf(w4.x, x4.x, fmaf(w4.y, x4.y, fmaf(w4.z, x4.z, fmaf(w4.w, x4.w, h1b))));
          }
          sc_h1[g * 80 + 64 + lane] = fmaxf(h1b, 0.f);
        }
      }

      // h2 = relu(mlp_w2 @ h1 + b2) ; z = mlp_w3 @ h2 + b3 ; sigmoid
      float h2 = mlp_b2[lane];
      {
        const float* wr = mlp_w2 + lane * MLPD;
        const float* hb = sc_h1 + g * 80;
#pragma unroll 2
        for (int k = 0; k < MLPD; k += 4) {
          const float4 w4 = *(const float4*)(wr + k);
          const float4 h4 = *(const float4*)&hb[k];
          h2 = fmaf(w4.x, h4.x, fmaf(w4.y, h4.y, fmaf(w4.z, h4.z, fmaf(w4.w, h4.w, h2))));
        }
      }
      h2 = fmaxf(h2, 0.f);
      float zz = mlp_w3[lane] * h2;
#pragma unroll
      for (int off = 32; off >= 1; off >>= 1) zz += __shfl_xor(zz, off, 64);
      if (lane == 0) out[bw] = 1.f / (1.f + __expf(-(zz + mlp_b3[0])));
    }
  }
}

extern "C" void kernel_launch(void* const* d_in, const int* in_sizes, int n_in,
                              void* d_out, int out_size, void* d_ws, size_t ws_size,
                              hipStream_t stream) {
  tempme_fused<<<NBLK, NT, 0, stream>>>(
      (const int*)d_in[0],    // node_idx
      (const int*)d_in[1],    // edge_idx
      (const int*)d_in[2],    // cat_feat
      (const float*)d_in[3],  // t_records
      (const float*)d_in[4],  // edge_identify
      // d_in[5] cut_time_l unused by reference
      (const float*)d_in[6],  // node_embed
      (const float*)d_in[7],  // edge_embed
      (const float*)d_in[8],  // basis_freq
      (const float*)d_in[9],  // phase
      (const float*)d_in[10], (const float*)d_in[11],  // lin_event
      (const float*)d_in[12], (const float*)d_in[13],  // gcn1
      (const float*)d_in[14], (const float*)d_in[15],  // gcn2
      (const float*)d_in[16], (const float*)d_in[17],  // att_w1
      (const float*)d_in[18], (const float*)d_in[19],  // att_w2
      (const float*)d_in[20], (const float*)d_in[21],  // att_m1
      (const float*)d_in[22], (const float*)d_in[23],  // att_m2
      (const float*)d_in[24], (const float*)d_in[25],  // mlp1
      (const float*)d_in[26], (const float*)d_in[27],  // mlp2
      (const float*)d_in[28], (const float*)d_in[29],  // mlp3
      (float*)d_out);
}

// Round 5
// 1173.397 us; speedup vs baseline: 2.9612x; 1.2973x over previous
//
#include <hip/hip_runtime.h>
#include <hip/hip_bf16.h>
#include <math.h>

// Problem constants
#define NW    32768   // B*W = 512*64 windows
#define G     8       // windows per block
#define NBLK  (NW / G)
#define NT    256

// Dims
#define ND    172     // NODE_DIM = EDGE_DIM = TIME_DIM
#define EVD   347     // EVENT_DIM
#define HID   64
#define D2    128
#define MLPD  76

// LDS byte layout (34816 B total -> 4 blocks/CU). Liveness overlays:
//  EF  bf16[32][360] @ [0,23040)      phases 0-1 (rows 24-31 garbage, K-pad 347..351 zeroed)
//  EV  bf16[24][184] @ [25600,34432)  phase 1 out, dead after 2a
//  U   bf16[64][200] @ [0,25600)      2a out (rows 0-23 u0, 32-55 u1; K-pad 172..191 zeroed)
//  H   bf16[64][72]  @ [25600,34816)  2b out
//  FEAT f32[8*384]   @ [0,12288)      2c out
//  SC   f32[2816]    @ [12288,23552)  phase-3 scratch
#define B_EF   0
#define B_EV   25600
#define B_U    0
#define B_H    25600
#define B_FEAT 0
#define B_SC   12288
#define LDS_BYTES 34816

#define EFS 360   // EF row stride (bf16)
#define EVS 184   // EV row stride
#define US  200   // U row stride
#define HS  72    // H row stride

typedef __attribute__((ext_vector_type(8))) short bf16x8;
typedef __attribute__((ext_vector_type(4))) float f32x4;

static __device__ __forceinline__ short f2bf(float f) {
  union { __hip_bfloat16 h; short s; } u;
  u.h = __float2bfloat16(f);
  return u.s;
}

__global__ __launch_bounds__(256) void tempme_fused(
    const int*   __restrict__ node_idx,      // (NW, 6)
    const int*   __restrict__ edge_idx,      // (NW, 3)
    const int*   __restrict__ cat_feat,      // (NW, 1)
    const float* __restrict__ t_records,     // (NW, 3)
    const float* __restrict__ edge_identify, // (NW, 3, 3)
    const float* __restrict__ node_embed,    // (10000, 172)
    const float* __restrict__ edge_embed,    // (200000, 172)
    const float* __restrict__ basis_freq,    // (172,)
    const float* __restrict__ phase,         // (172,)
    const float* __restrict__ lin_event_w,   // (172, 347)
    const float* __restrict__ lin_event_b,   // (172,)
    const float* __restrict__ gcn_w1,        // (64, 172)
    const float* __restrict__ gcn_b1,        // (64,)
    const float* __restrict__ gcn_w2,        // (64, 64)
    const float* __restrict__ gcn_b2,        // (64,)
    const float* __restrict__ att_w1_w,      // (128, 128)
    const float* __restrict__ att_w1_b,      // (128,)
    const float* __restrict__ att_w2_w,      // (128, 128)
    const float* __restrict__ att_w2_b,      // (128,)
    const float* __restrict__ att_m1_w,      // (64, 128)
    const float* __restrict__ att_m1_b,      // (64,)
    const float* __restrict__ att_m2_w,      // (64, 64)
    const float* __restrict__ att_m2_b,      // (64,)
    const float* __restrict__ mlp_w1,        // (76, 76)
    const float* __restrict__ mlp_b1,        // (76,)
    const float* __restrict__ mlp_w2,        // (64, 76)
    const float* __restrict__ mlp_b2,        // (64,)
    const float* __restrict__ mlp_w3,        // (1, 64)
    const float* __restrict__ mlp_b3,        // (1,)
    float*       __restrict__ out)           // (NW,)
{
  __shared__ __align__(16) unsigned char smem[LDS_BYTES];
  __hip_bfloat16* EF  = (__hip_bfloat16*)&smem[B_EF];
  __hip_bfloat16* EV  = (__hip_bfloat16*)&smem[B_EV];
  __hip_bfloat16* U   = (__hip_bfloat16*)&smem[B_U];
  __hip_bfloat16* Hb  = (__hip_bfloat16*)&smem[B_H];
  float*          FEAT= (float*)&smem[B_FEAT];
  float*          SC  = (float*)&smem[B_SC];

  const int tid  = threadIdx.x;
  const int lane = tid & 63;
  const int wv   = tid >> 6;
  const int q    = lane >> 4;   // MFMA quad
  const int mr   = lane & 15;   // MFMA row/col-within-tile
  const int bw0  = blockIdx.x * G;

  // ============ phase 0: build ef bf16[24][360]; wave w owns rows w,w+4,.. ============
#pragma unroll 1
  for (int i = 0; i < 6; ++i) {
    const int r   = wv + 4 * i;
    const int g   = r / 3;
    const int l   = r - 3 * g;
    const int bw  = bw0 + g;
    const int rid = bw * 3 + l;
    const int e   = edge_idx[rid];
    const float dt = t_records[bw * 3 + 2] - t_records[rid];
    const float* erow = edge_embed + (long)e * ND;
#pragma unroll 2
    for (int c = 0; c < 6; ++c) {
      const int k = c * 64 + lane;   // 0..383
      if (k < 352) {                 // 347..351 = K-pad (zero); 352+ untouched
        float v = 0.f;
        if (k < ND) v = erow[k];
        else if (k < ND + 3) v = edge_identify[rid * 3 + (k - ND)];
        else if (k < EVD) {
          const int d = k - (ND + 3);
          v = __cosf(fmaf(dt, basis_freq[d], phase[d]));
        }
        EF[r * EFS + k] = __float2bfloat16(v);
      }
    }
  }
  __syncthreads();

  // ============ phase 1 (MFMA): EV[24][172] = EF[24][347] @ lin_event_w^T ============
  // C tiles: m-tiles {0,1} (rows 0..31), n-tiles 0..10 (cols 0..175).
  // Wave w owns n-tiles {w, w+4, w+8} (wave 3: {3,7}).
  {
    const int nnt = (wv == 3) ? 2 : 3;
    f32x4 acc[3][2];
#pragma unroll
    for (int t = 0; t < 3; ++t)
#pragma unroll
      for (int mt = 0; mt < 2; ++mt) acc[t][mt] = (f32x4){0.f, 0.f, 0.f, 0.f};

#pragma unroll 2
    for (int ks = 0; ks < 11; ++ks) {
      const int k0 = ks * 32 + q * 8;
      const bf16x8 a0 = *(const bf16x8*)&EF[(0 * 16 + mr) * EFS + k0];
      const bf16x8 a1 = *(const bf16x8*)&EF[(1 * 16 + mr) * EFS + k0];
#pragma unroll 1
      for (int t = 0; t < nnt; ++t) {
        const int n = (wv + 4 * t) * 16 + mr;
        bf16x8 b = {0, 0, 0, 0, 0, 0, 0, 0};
        if (n < ND) {
          const float* wp = lin_event_w + n * EVD + k0;  // rows odd-length: scalar loads
          const int rem = EVD - k0;                       // >= 3 always
#pragma unroll
          for (int j = 0; j < 8; ++j)
            if (j < rem) b[j] = f2bf(wp[j]);
        }
        acc[t][0] = __builtin_amdgcn_mfma_f32_16x16x32_bf16(a0, b, acc[t][0], 0, 0, 0);
        acc[t][1] = __builtin_amdgcn_mfma_f32_16x16x32_bf16(a1, b, acc[t][1], 0, 0, 0);
      }
    }
    // write EV (C layout: col=lane&15 -> n, row=q*4+reg (+16*mt) -> m); rows >=24 discarded
#pragma unroll 1
    for (int t = 0; t < nnt; ++t) {
      const int n = (wv + 4 * t) * 16 + mr;
      const float bo = (n < ND) ? lin_event_b[n] : 0.f;
#pragma unroll
      for (int mt = 0; mt < 2; ++mt)
#pragma unroll
        for (int reg = 0; reg < 4; ++reg) {
          const int m = mt * 16 + q * 4 + reg;
          if (m < 24) EV[m * EVS + n] = __float2bfloat16(acc[t][mt][reg] + bo);
        }
    }
  }
  __syncthreads();

  // ============ phase 2a: U rows: u0=s+relu(t+e) (rows 0..23), u1=t+relu(s+e) (rows 32..55) ============
#pragma unroll 1
  for (int i = 0; i < 6; ++i) {
    const int r  = wv + 4 * i;
    const int g  = r / 3;
    const int l  = r - 3 * g;
    const int bw = bw0 + g;
    const int si = node_idx[bw * 6 + 2 * l];
    const int ti = node_idx[bw * 6 + 2 * l + 1];
#pragma unroll
    for (int c = 0; c < 3; ++c) {
      const int k = c * 64 + lane;  // 0..191
      float u0v = 0.f, u1v = 0.f;
      if (k < ND) {
        const float e = __bfloat162float(EV[r * EVS + k]);
        const float s = node_embed[(long)si * ND + k];
        const float t = node_embed[(long)ti * ND + k];
        u0v = s + fmaxf(t + e, 0.f);
        u1v = t + fmaxf(s + e, 0.f);
      }
      // k in [172,192) writes zeros = K-pad for phase 2b
      U[r * US + k]        = __float2bfloat16(u0v);
      U[(32 + r) * US + k] = __float2bfloat16(u1v);
    }
  }
  __syncthreads();

  // ============ phase 2b (MFMA): H[64][64] = relu(U[64][192] @ gcn_w1^T + b1) ============
  // Wave w owns m-tile w; all 4 n-tiles.
  {
    f32x4 acc[4];
#pragma unroll
    for (int nt = 0; nt < 4; ++nt) acc[nt] = (f32x4){0.f, 0.f, 0.f, 0.f};
#pragma unroll 2
    for (int ks = 0; ks < 6; ++ks) {
      const int k0 = ks * 32 + q * 8;
      const bf16x8 a = *(const bf16x8*)&U[(wv * 16 + mr) * US + k0];
#pragma unroll 1
      for (int nt = 0; nt < 4; ++nt) {
        const int n = nt * 16 + mr;  // < 64, always valid
        const float* wp = gcn_w1 + n * ND + k0;
        bf16x8 b;
        if (k0 + 8 <= ND) {  // rows are 16B-aligned (172*4 % 16 == 0)
          const f32x4 lo = *(const f32x4*)wp;
          const f32x4 hi = *(const f32x4*)(wp + 4);
#pragma unroll
          for (int j = 0; j < 4; ++j) { b[j] = f2bf(lo[j]); b[4 + j] = f2bf(hi[j]); }
        } else {
          const int rem = ND - k0;  // may be <= 0
#pragma unroll
          for (int j = 0; j < 8; ++j) b[j] = (j < rem) ? f2bf(wp[j]) : (short)0;
        }
        acc[nt] = __builtin_amdgcn_mfma_f32_16x16x32_bf16(a, b, acc[nt], 0, 0, 0);
      }
    }
#pragma unroll 1
    for (int nt = 0; nt < 4; ++nt) {
      const int j = nt * 16 + mr;
      const float b1 = gcn_b1[j];
#pragma unroll
      for (int reg = 0; reg < 4; ++reg) {
        const int m = wv * 16 + q * 4 + reg;
        Hb[m * HS + j] = __float2bfloat16(fmaxf(acc[nt][reg] + b1, 0.f));
      }
    }
  }
  __syncthreads();

  // ============ phase 2c (MFMA): FEAT = H[64][64] @ gcn_w2^T + b2 ============
  {
    f32x4 acc[4];
#pragma unroll
    for (int nt = 0; nt < 4; ++nt) acc[nt] = (f32x4){0.f, 0.f, 0.f, 0.f};
#pragma unroll
    for (int ks = 0; ks < 2; ++ks) {
      const int k0 = ks * 32 + q * 8;
      const bf16x8 a = *(const bf16x8*)&Hb[(wv * 16 + mr) * HS + k0];
#pragma unroll 1
      for (int nt = 0; nt < 4; ++nt) {
        const int n = nt * 16 + mr;
        const float* wp = gcn_w2 + n * HID + k0;  // aligned, K=64 exact
        const f32x4 lo = *(const f32x4*)wp;
        const f32x4 hi = *(const f32x4*)(wp + 4);
        bf16x8 b;
#pragma unroll
        for (int j = 0; j < 4; ++j) { b[j] = f2bf(lo[j]); b[4 + j] = f2bf(hi[j]); }
        acc[nt] = __builtin_amdgcn_mfma_f32_16x16x32_bf16(a, b, acc[nt], 0, 0, 0);
      }
    }
    // write feat[g][l][d*64+j]; rows: 0..23 -> d0, 32..55 -> d1, rest discarded
#pragma unroll 1
    for (int nt = 0; nt < 4; ++nt) {
      const int j = nt * 16 + mr;
      const float b2 = gcn_b2[j];
#pragma unroll
      for (int reg = 0; reg < 4; ++reg) {
        const int m = wv * 16 + q * 4 + reg;
        int d = -1, r = 0;
        if (m < 24) { d = 0; r = m; }
        else if (m >= 32 && m < 56) { d = 1; r = m - 32; }
        if (d >= 0) {
          const int g = r / 3;
          const int l = r - 3 * g;
          FEAT[g * 384 + l * 128 + d * HID + j] = acc[nt][reg] + b2;
        }
      }
    }
  }
  __syncthreads();

  // ============ phase 3: attention + MLP head (fp32 VALU; wave-private LDS slots) ============
  {
    float* sc_out = SC;           // 8*128
    float* sc_m1  = SC + 1024;    // 8*64
    float* sc_x   = SC + 1536;    // 8*80
    float* sc_h1  = SC + 2176;    // 8*80
#pragma unroll 1
    for (int it = 0; it < 2; ++it) {
      const int g  = wv * 2 + it;
      const int bw = bw0 + g;
      const float* fg = &FEAT[g * 384];

      // Wp = att_w1 @ src + b1 ; lane owns d = lane, lane+64
      float p0 = att_w1_b[lane], p1 = att_w1_b[lane + 64];
      {
        const float* r0 = att_w1_w + lane * D2;
        const float* r1 = att_w1_w + (lane + 64) * D2;
#pragma unroll 2
        for (int e = 0; e < D2; e += 4) {
          const float4 f4 = *(const float4*)&fg[256 + e];
          const float4 a4 = *(const float4*)(r0 + e);
          const float4 b4 = *(const float4*)(r1 + e);
          p0 = fmaf(a4.x, f4.x, fmaf(a4.y, f4.y, fmaf(a4.z, f4.z, fmaf(a4.w, f4.w, p0))));
          p1 = fmaf(b4.x, f4.x, fmaf(b4.y, f4.y, fmaf(b4.z, f4.z, fmaf(b4.w, f4.w, p1))));
        }
      }
      // Wq[k] = att_w2 @ feat[k] + b2, k = 0,1
      float q00 = att_w2_b[lane], q01 = att_w2_b[lane + 64];
      float q10 = q00, q11 = q01;
      {
        const float* r0 = att_w2_w + lane * D2;
        const float* r1 = att_w2_w + (lane + 64) * D2;
#pragma unroll 2
        for (int e = 0; e < D2; e += 4) {
          const float4 a4 = *(const float4*)(r0 + e);
          const float4 b4 = *(const float4*)(r1 + e);
          const float4 f0 = *(const float4*)&fg[e];
          const float4 f1 = *(const float4*)&fg[128 + e];
          q00 = fmaf(a4.x, f0.x, fmaf(a4.y, f0.y, fmaf(a4.z, f0.z, fmaf(a4.w, f0.w, q00))));
          q01 = fmaf(b4.x, f0.x, fmaf(b4.y, f0.y, fmaf(b4.z, f0.z, fmaf(b4.w, f0.w, q01))));
          q10 = fmaf(a4.x, f1.x, fmaf(a4.y, f1.y, fmaf(a4.z, f1.z, fmaf(a4.w, f1.w, q10))));
          q11 = fmaf(b4.x, f1.x, fmaf(b4.y, f1.y, fmaf(b4.z, f1.z, fmaf(b4.w, f1.w, q11))));
        }
      }
      // scores (2 keys) + softmax (wave reductions)
      float s0 = p0 * q00 + p1 * q01;
      float s1 = p0 * q10 + p1 * q11;
#pragma unroll
      for (int off = 32; off >= 1; off >>= 1) {
        s0 += __shfl_xor(s0, off, 64);
        s1 += __shfl_xor(s1, off, 64);
      }
      const float mx = fmaxf(s0, s1);
      const float e0 = __expf(s0 - mx), e1 = __expf(s1 - mx);
      const float inv = 1.f / (e0 + e1);
      const float a0 = e0 * inv, a1 = e1 * inv;
      sc_out[g * 128 + lane]      = fg[256 + lane]      + a0 * q00 + a1 * q10;
      sc_out[g * 128 + 64 + lane] = fg[256 + 64 + lane] + a0 * q01 + a1 * q11;

      // m1 = relu(att_m1 @ out + b)
      float m1 = att_m1_b[lane];
      {
        const float* wr = att_m1_w + lane * D2;
        const float* ob = sc_out + g * 128;
#pragma unroll 2
        for (int d = 0; d < D2; d += 4) {
          const float4 w4 = *(const float4*)(wr + d);
          const float4 o4 = *(const float4*)&ob[d];
          m1 = fmaf(w4.x, o4.x, fmaf(w4.y, o4.y, fmaf(w4.z, o4.z, fmaf(w4.w, o4.w, m1))));
        }
      }
      sc_m1[g * 64 + lane] = fmaxf(m1, 0.f);

      // h = att_m2 @ m1 + b
      float hv = att_m2_b[lane];
      {
        const float* wr = att_m2_w + lane * HID;
        const float* mb = sc_m1 + g * 64;
#pragma unroll 2
        for (int d = 0; d < HID; d += 4) {
          const float4 w4 = *(const float4*)(wr + d);
          const float4 m4 = *(const float4*)&mb[d];
          hv = fmaf(w4.x, m4.x, fmaf(w4.y, m4.y, fmaf(w4.z, m4.z, fmaf(w4.w, m4.w, hv))));
        }
      }
      // x = concat(h, one_hot(cat,12))
      sc_x[g * 80 + lane] = hv;
      if (lane < 12) {
        const int cat = cat_feat[bw];
        sc_x[g * 80 + 64 + lane] = (cat == lane) ? 1.f : 0.f;
      }

      // h1 = relu(mlp_w1 @ x + b1) : 76 outputs
      const float* xb = sc_x + g * 80;
      {
        float h1a = mlp_b1[lane];
        const float* wr = mlp_w1 + lane * MLPD;
#pragma unroll 2
        for (int k = 0; k < MLPD; k += 4) {
          const float4 w4 = *(const float4*)(wr + k);
          const float4 x4 = *(const float4*)&xb[k];
          h1a = fmaf(w4.x, x4.x, fmaf(w4.y, x4.y, fmaf(w4.z, x4.z, fmaf(w4.w, x4.w, h1a))));
        }
        sc_h1[g * 80 + lane] = fmaxf(h1a, 0.f);
        if (lane < 12) {
          float h1b = mlp_b1[64 + lane];
          const float* wr2 = mlp_w1 + (64 + lane) * MLPD;
#pragma unroll 2
          for (int k = 0; k < MLPD; k += 4) {
            const float4 w4 = *(const float4*)(wr2 + k);
            const float4 x4 = *(const float4*)&xb[k];
            h1b = fmaf(w4.x, x4.x, fmaf(w4.y, x4.y, fmaf(w4.z, x4.z, fmaf(w4.w, x4.w, h1b))));
          }
          sc_h1[g * 80 + 64 + lane] = fmaxf(h1b, 0.f);
        }
      }

      // h2 = relu(mlp_w2 @ h1 + b2) ; z = mlp_w3 @ h2 + b3 ; sigmoid
      float h2 = mlp_b2[lane];
      {
        const float* wr = mlp_w2 + lane * MLPD;
        const float* hb = sc_h1 + g * 80;
#pragma unroll 2
        for (int k = 0; k < MLPD; k += 4) {
          const float4 w4 = *(const float4*)(wr + k);
          const float4 h4 = *(const float4*)&hb[k];
          h2 = fmaf(w4.x, h4.x, fmaf(w4.y, h4.y, fmaf(w4.z, h4.z, fmaf(w4.w, h4.w, h2))));
        }
      }
      h2 = fmaxf(h2, 0.f);
      float zz = mlp_w3[lane] * h2;
#pragma unroll
      for (int off = 32; off >= 1; off >>= 1) zz += __shfl_xor(zz, off, 64);
      if (lane == 0) out[bw] = 1.f / (1.f + __expf(-(zz + mlp_b3[0])));
    }
  }
}

extern "C" void kernel_launch(void* const* d_in, const int* in_sizes, int n_in,
                              void* d_out, int out_size, void* d_ws, size_t ws_size,
                              hipStream_t stream) {
  tempme_fused<<<NBLK, NT, 0, stream>>>(
      (const int*)d_in[0],    // node_idx
      (const int*)d_in[1],    // edge_idx
      (const int*)d_in[2],    // cat_feat
      (const float*)d_in[3],  // t_records
      (const float*)d_in[4],  // edge_identify
      // d_in[5] cut_time_l unused by reference
      (const float*)d_in[6],  // node_embed
      (const float*)d_in[7],  // edge_embed
      (const float*)d_in[8],  // basis_freq
      (const float*)d_in[9],  // phase
      (const float*)d_in[10], (const float*)d_in[11],  // lin_event
      (const float*)d_in[12], (const float*)d_in[13],  // gcn1
      (const float*)d_in[14], (const float*)d_in[15],  // gcn2
      (const float*)d_in[16], (const float*)d_in[17],  // att_w1
      (const float*)d_in[18], (const float*)d_in[19],  // att_w2
      (const float*)d_in[20], (const float*)d_in[21],  // att_m1
      (const float*)d_in[22], (const float*)d_in[23],  // att_m2
      (const float*)d_in[24], (const float*)d_in[25],  // mlp1
      (const float*)d_in[26], (const float*)d_in[27],  // mlp2
      (const float*)d_in[28], (const float*)d_in[29],  // mlp3
      (float*)d_out);
}

// Round 6
// 718.326 us; speedup vs baseline: 4.8372x; 1.6335x over previous
//
#include <hip/hip_runtime.h>
#include <hip/hip_bf16.h>
#include <math.h>

// Problem constants
#define NW    32768   // B*W = 512*64 windows
#define G     8       // windows per block
#define NBLK  (NW / G)
#define NT    256

// Dims
#define ND    172     // NODE_DIM = EDGE_DIM = TIME_DIM
#define EVD   347     // EVENT_DIM
#define HID   64
#define D2    128
#define MLPD  76

// ---- Workspace: bf16 weights pre-packed in MFMA B-fragment order ----
// fragment = 64 lanes x 8 bf16; addr = (frag_id*64 + lane)*8; lane=(q<<4)|mr;
// element j of lane: B[n = nt*16+mr][k = ks*32+q*8+j] (0 if OOB).
//   W1P : lin_event_w, nt in [0,11), ks in [0,11)  -> frags [0,121)
//   G1P : gcn_w1,      nt in [0,4),  ks in [0,6)   -> frags [121,145)
//   G2P : gcn_w2,      nt in [0,4),  ks in [0,2)   -> frags [145,153)
//   ATTP: att_w1_w (n<128) / att_w2_w (n>=128), nt in [0,16), ks in [0,4) -> frags [153,217)
#define W1OFF  0
#define G1OFF  (121 * 512)
#define G2OFF  (145 * 512)
#define ATTOFF (153 * 512)
#define NFRAG  217          // total ws = 217*512 bf16 = 222208 B

// ---- LDS byte layout (34816 B -> 4 blocks/CU), liveness overlays ----
//  EF   bf16[32][360] @ 0      (23040)  phases 0-1 (rows 24+ garbage)
//  EV   bf16[24][184] @ 25600  (8832)   phase-1 out, dead after 2a
//  U    bf16[64][200] @ 0      (25600)  2a out (rows 0-23 u0, 32-55 u1)
//  H    bf16[64][72]  @ 25600  (9216)   2b out
//  FEATB bf16[32][136]@ 0      (8704)   2c out (rows 0-23 valid)
//  SRCF f32[8][128]   @ 20992  (4096)   2c out (src feat, l==2 rows)
//  PQ   f32[24][128]  @ 8704   (12288)  2d out (Wp for l==2, Wq else)
//  SC   f32[2816]     @ 0      (11264)  phase-3 scratch (FEATB dead)
#define B_EF    0
#define B_EV    25600
#define B_U     0
#define B_H     25600
#define B_FEATB 0
#define B_SRCF  20992
#define B_PQ    8704
#define B_SC    0
#define LDS_BYTES 34816

#define EFS 360
#define EVS 184
#define US  200
#define HS  72
#define FBS 136

typedef __attribute__((ext_vector_type(8))) short bf16x8;
typedef __attribute__((ext_vector_type(4))) float f32x4;

static __device__ __forceinline__ short f2bf(float f) {
  union { __hip_bfloat16 h; short s; } u;
  u.h = __float2bfloat16(f);
  return u.s;
}
static __device__ __forceinline__ float bf2f(short s) {
  union { float f; unsigned u; } u;
  u.u = ((unsigned)(unsigned short)s) << 16;
  return u.f;
}

// ============ prep: pack all MFMA weights as bf16 fragments into ws ============
__global__ __launch_bounds__(256) void prep_weights(
    const float* __restrict__ w1, const float* __restrict__ g1,
    const float* __restrict__ g2, const float* __restrict__ a1,
    const float* __restrict__ a2, short* __restrict__ ws)
{
  const int t = blockIdx.x * 256 + threadIdx.x;
  if (t >= NFRAG * 64) return;
  const int fid  = t >> 6;
  const int lane = t & 63;
  const int q = lane >> 4, mr = lane & 15;
  bf16x8 o;
  if (fid < 121) {
    const int nt = fid / 11, ks = fid - 11 * nt;
    const int n = nt * 16 + mr, k0 = ks * 32 + q * 8;
#pragma unroll
    for (int j = 0; j < 8; ++j) {
      const int k = k0 + j;
      o[j] = (n < ND && k < EVD) ? f2bf(w1[n * EVD + k]) : (short)0;
    }
  } else if (fid < 145) {
    const int f = fid - 121, nt = f / 6, ks = f - 6 * nt;
    const int n = nt * 16 + mr, k0 = ks * 32 + q * 8;
#pragma unroll
    for (int j = 0; j < 8; ++j) {
      const int k = k0 + j;
      o[j] = (k < ND) ? f2bf(g1[n * ND + k]) : (short)0;
    }
  } else if (fid < 153) {
    const int f = fid - 145, nt = f / 2, ks = f - 2 * nt;
    const int n = nt * 16 + mr, k0 = ks * 32 + q * 8;
#pragma unroll
    for (int j = 0; j < 8; ++j) o[j] = f2bf(g2[n * HID + k0 + j]);
  } else {
    const int f = fid - 153, nt = f / 4, ks = f - 4 * nt;
    const int n = nt * 16 + mr, k0 = ks * 32 + q * 8;
    const float* src = (n < D2) ? (a1 + n * D2) : (a2 + (n - D2) * D2);
#pragma unroll
    for (int j = 0; j < 8; ++j) o[j] = f2bf(src[k0 + j]);
  }
  *(bf16x8*)&ws[(long)t * 8] = o;
}

__global__ __launch_bounds__(256) void tempme_fused(
    const int*   __restrict__ node_idx,      // (NW, 6)
    const int*   __restrict__ edge_idx,      // (NW, 3)
    const int*   __restrict__ cat_feat,      // (NW, 1)
    const float* __restrict__ t_records,     // (NW, 3)
    const float* __restrict__ edge_identify, // (NW, 3, 3)
    const float* __restrict__ node_embed,    // (10000, 172)
    const float* __restrict__ edge_embed,    // (200000, 172)
    const float* __restrict__ basis_freq,    // (172,)
    const float* __restrict__ phase,         // (172,)
    const float* __restrict__ lin_event_b,   // (172,)
    const float* __restrict__ gcn_b1,        // (64,)
    const float* __restrict__ gcn_b2,        // (64,)
    const float* __restrict__ att_w1_b,      // (128,)
    const float* __restrict__ att_w2_b,      // (128,)
    const float* __restrict__ att_m1_w,      // (64, 128)
    const float* __restrict__ att_m1_b,      // (64,)
    const float* __restrict__ att_m2_w,      // (64, 64)
    const float* __restrict__ att_m2_b,      // (64,)
    const float* __restrict__ mlp_w1,        // (76, 76)
    const float* __restrict__ mlp_b1,        // (76,)
    const float* __restrict__ mlp_w2,        // (64, 76)
    const float* __restrict__ mlp_b2,        // (64,)
    const float* __restrict__ mlp_w3,        // (1, 64)
    const float* __restrict__ mlp_b3,        // (1,)
    const short* __restrict__ ws,            // packed bf16 weights
    float*       __restrict__ out)           // (NW,)
{
  __shared__ __align__(16) unsigned char smem[LDS_BYTES];
  short* EF    = (short*)&smem[B_EF];
  short* EV    = (short*)&smem[B_EV];
  short* U     = (short*)&smem[B_U];
  short* Hs    = (short*)&smem[B_H];
  short* FEATB = (short*)&smem[B_FEATB];
  float* SRCF  = (float*)&smem[B_SRCF];
  float* PQ    = (float*)&smem[B_PQ];
  float* SC    = (float*)&smem[B_SC];

  const int tid  = threadIdx.x;
  const int lane = tid & 63;
  const int wv   = tid >> 6;
  const int q    = lane >> 4;   // MFMA quad
  const int mr   = lane & 15;   // MFMA row/col-within-tile
  const int bw0  = blockIdx.x * G;

  // ============ phase 0: build ef bf16[24][360]; wave w owns rows w,w+4,.. ============
#pragma unroll 1
  for (int i = 0; i < 6; ++i) {
    const int r   = wv + 4 * i;
    const int g   = r / 3;
    const int l   = r - 3 * g;
    const int bw  = bw0 + g;
    const int rid = bw * 3 + l;
    const int e   = edge_idx[rid];
    const float dt = t_records[bw * 3 + 2] - t_records[rid];
    const float* erow = edge_embed + (long)e * ND;
#pragma unroll 2
    for (int c = 0; c < 6; ++c) {
      const int k = c * 64 + lane;   // 0..383
      if (k < 352) {                 // 347..351 = K-pad (zero)
        float v = 0.f;
        if (k < ND) v = erow[k];
        else if (k < ND + 3) v = edge_identify[rid * 3 + (k - ND)];
        else if (k < EVD) {
          const int d = k - (ND + 3);
          v = __cosf(fmaf(dt, basis_freq[d], phase[d]));
        }
        EF[r * EFS + k] = f2bf(v);
      }
    }
  }
  __syncthreads();

  // ============ phase 1 (MFMA): EV[24][172] = EF[24][347] @ lin_event_w^T ============
  {
    const int nnt = (wv == 3) ? 2 : 3;   // wave w owns n-tiles {w, w+4, w+8}
    f32x4 acc[3][2];
#pragma unroll
    for (int t = 0; t < 3; ++t)
#pragma unroll
      for (int mt = 0; mt < 2; ++mt) acc[t][mt] = (f32x4){0.f, 0.f, 0.f, 0.f};

#pragma unroll 2
    for (int ks = 0; ks < 11; ++ks) {
      const int k0 = ks * 32 + q * 8;
      const bf16x8 a0 = *(const bf16x8*)&EF[mr * EFS + k0];
      const bf16x8 a1 = *(const bf16x8*)&EF[(16 + mr) * EFS + k0];
#pragma unroll 1
      for (int t = 0; t < nnt; ++t) {
        const int nt = wv + 4 * t;
        const bf16x8 b = *(const bf16x8*)&ws[W1OFF + ((nt * 11 + ks) * 64 + lane) * 8];
        acc[t][0] = __builtin_amdgcn_mfma_f32_16x16x32_bf16(a0, b, acc[t][0], 0, 0, 0);
        acc[t][1] = __builtin_amdgcn_mfma_f32_16x16x32_bf16(a1, b, acc[t][1], 0, 0, 0);
      }
    }
#pragma unroll 1
    for (int t = 0; t < nnt; ++t) {
      const int n = (wv + 4 * t) * 16 + mr;
      const float bo = (n < ND) ? lin_event_b[n] : 0.f;
#pragma unroll
      for (int mt = 0; mt < 2; ++mt)
#pragma unroll
        for (int reg = 0; reg < 4; ++reg) {
          const int m = mt * 16 + q * 4 + reg;
          if (m < 24) EV[m * EVS + n] = f2bf(acc[t][mt][reg] + bo);
        }
    }
  }
  __syncthreads();

  // ============ phase 2a: U rows: u0=s+relu(t+e) (0..23), u1=t+relu(s+e) (32..55) ============
#pragma unroll 1
  for (int i = 0; i < 6; ++i) {
    const int r  = wv + 4 * i;
    const int g  = r / 3;
    const int l  = r - 3 * g;
    const int bw = bw0 + g;
    const int si = node_idx[bw * 6 + 2 * l];
    const int ti = node_idx[bw * 6 + 2 * l + 1];
#pragma unroll
    for (int c = 0; c < 3; ++c) {
      const int k = c * 64 + lane;  // 0..191
      float u0v = 0.f, u1v = 0.f;
      if (k < ND) {
        const float e = bf2f(EV[r * EVS + k]);
        const float s = node_embed[(long)si * ND + k];
        const float t = node_embed[(long)ti * ND + k];
        u0v = s + fmaxf(t + e, 0.f);
        u1v = t + fmaxf(s + e, 0.f);
      }
      U[r * US + k]        = f2bf(u0v);   // k in [172,192) zero = K-pad
      U[(32 + r) * US + k] = f2bf(u1v);
    }
  }
  __syncthreads();

  // ============ phase 2b (MFMA): H[64][64] = relu(U[64][192] @ gcn_w1^T + b1) ============
  {
    f32x4 acc[4];
#pragma unroll
    for (int nt = 0; nt < 4; ++nt) acc[nt] = (f32x4){0.f, 0.f, 0.f, 0.f};
#pragma unroll 2
    for (int ks = 0; ks < 6; ++ks) {
      const int k0 = ks * 32 + q * 8;
      const bf16x8 a = *(const bf16x8*)&U[(wv * 16 + mr) * US + k0];
#pragma unroll 1
      for (int nt = 0; nt < 4; ++nt) {
        const bf16x8 b = *(const bf16x8*)&ws[G1OFF + ((nt * 6 + ks) * 64 + lane) * 8];
        acc[nt] = __builtin_amdgcn_mfma_f32_16x16x32_bf16(a, b, acc[nt], 0, 0, 0);
      }
    }
#pragma unroll 1
    for (int nt = 0; nt < 4; ++nt) {
      const int j = nt * 16 + mr;
      const float b1 = gcn_b1[j];
#pragma unroll
      for (int reg = 0; reg < 4; ++reg) {
        const int m = wv * 16 + q * 4 + reg;
        Hs[m * HS + j] = f2bf(fmaxf(acc[nt][reg] + b1, 0.f));
      }
    }
  }
  __syncthreads();

  // ============ phase 2c (MFMA): FEATB/SRCF = H @ gcn_w2^T + b2 ============
  {
    f32x4 acc[4];
#pragma unroll
    for (int nt = 0; nt < 4; ++nt) acc[nt] = (f32x4){0.f, 0.f, 0.f, 0.f};
#pragma unroll
    for (int ks = 0; ks < 2; ++ks) {
      const int k0 = ks * 32 + q * 8;
      const bf16x8 a = *(const bf16x8*)&Hs[(wv * 16 + mr) * HS + k0];
#pragma unroll 1
      for (int nt = 0; nt < 4; ++nt) {
        const bf16x8 b = *(const bf16x8*)&ws[G2OFF + ((nt * 2 + ks) * 64 + lane) * 8];
        acc[nt] = __builtin_amdgcn_mfma_f32_16x16x32_bf16(a, b, acc[nt], 0, 0, 0);
      }
    }
#pragma unroll 1
    for (int nt = 0; nt < 4; ++nt) {
      const int j = nt * 16 + mr;
      const float b2 = gcn_b2[j];
#pragma unroll
      for (int reg = 0; reg < 4; ++reg) {
        const int m = wv * 16 + q * 4 + reg;
        int d = -1, r = 0;
        if (m < 24) { d = 0; r = m; }
        else if (m >= 32 && m < 56) { d = 1; r = m - 32; }
        if (d >= 0) {
          const float v = acc[nt][reg] + b2;
          const int n = d * HID + j;
          FEATB[r * FBS + n] = f2bf(v);
          if (r % 3 == 2) SRCF[(r / 3) * 128 + n] = v;   // src feat, fp32
        }
      }
    }
  }
  __syncthreads();

  // ============ phase 2d (MFMA): PQ = feat @ [att_w1 | att_w2]^T + bias ============
  // M=24(+pad), N=256 (n<128: Wp-weights, n>=128: Wq-weights), K=128.
  // Row r keeps Wp if l==2, Wq if l in {0,1}.
  {
    f32x4 acc[4][2];
#pragma unroll
    for (int tt = 0; tt < 4; ++tt)
#pragma unroll
      for (int mt = 0; mt < 2; ++mt) acc[tt][mt] = (f32x4){0.f, 0.f, 0.f, 0.f};
#pragma unroll 2
    for (int ks = 0; ks < 4; ++ks) {
      const int k0 = ks * 32 + q * 8;
      const bf16x8 a0 = *(const bf16x8*)&FEATB[mr * FBS + k0];
      const bf16x8 a1 = *(const bf16x8*)&FEATB[(16 + mr) * FBS + k0];
#pragma unroll 1
      for (int tt = 0; tt < 4; ++tt) {
        const int nt = wv * 4 + tt;
        const bf16x8 b = *(const bf16x8*)&ws[ATTOFF + ((nt * 4 + ks) * 64 + lane) * 8];
        acc[tt][0] = __builtin_amdgcn_mfma_f32_16x16x32_bf16(a0, b, acc[tt][0], 0, 0, 0);
        acc[tt][1] = __builtin_amdgcn_mfma_f32_16x16x32_bf16(a1, b, acc[tt][1], 0, 0, 0);
      }
    }
#pragma unroll 1
    for (int tt = 0; tt < 4; ++tt) {
      const int n = (wv * 4 + tt) * 16 + mr;   // 0..255
      const float bias = (n < D2) ? att_w1_b[n] : att_w2_b[n - D2];
#pragma unroll
      for (int mt = 0; mt < 2; ++mt)
#pragma unroll
        for (int reg = 0; reg < 4; ++reg) {
          const int m = mt * 16 + q * 4 + reg;
          if (m < 24) {
            const int l = m % 3;
            if (l == 2) { if (n < D2)  PQ[m * 128 + n]       = acc[tt][mt][reg] + bias; }
            else        { if (n >= D2) PQ[m * 128 + (n - D2)] = acc[tt][mt][reg] + bias; }
          }
        }
    }
  }
  __syncthreads();

  // ============ phase 3: softmax/out + MLP head (fp32 VALU; wave-private slots) ============
  {
    float* sc_out = SC;           // 8*128
    float* sc_m1  = SC + 1024;    // 8*64
    float* sc_x   = SC + 1536;    // 8*80
    float* sc_h1  = SC + 2176;    // 8*80
#pragma unroll 1
    for (int it = 0; it < 2; ++it) {
      const int g  = wv * 2 + it;
      const int bw = bw0 + g;

      const float p0  = PQ[(3 * g + 2) * 128 + lane];
      const float p1  = PQ[(3 * g + 2) * 128 + 64 + lane];
      const float q00 = PQ[(3 * g + 0) * 128 + lane];
      const float q01 = PQ[(3 * g + 0) * 128 + 64 + lane];
      const float q10 = PQ[(3 * g + 1) * 128 + lane];
      const float q11 = PQ[(3 * g + 1) * 128 + 64 + lane];

      float s0 = p0 * q00 + p1 * q01;
      float s1 = p0 * q10 + p1 * q11;
#pragma unroll
      for (int off = 32; off >= 1; off >>= 1) {
        s0 += __shfl_xor(s0, off, 64);
        s1 += __shfl_xor(s1, off, 64);
      }
      const float mx = fmaxf(s0, s1);
      const float e0 = __expf(s0 - mx), e1 = __expf(s1 - mx);
      const float inv = 1.f / (e0 + e1);
      const float a0 = e0 * inv, a1 = e1 * inv;
      sc_out[g * 128 + lane]      = SRCF[g * 128 + lane]      + a0 * q00 + a1 * q10;
      sc_out[g * 128 + 64 + lane] = SRCF[g * 128 + 64 + lane] + a0 * q01 + a1 * q11;

      // m1 = relu(att_m1 @ out + b)
      float m1 = att_m1_b[lane];
      {
        const float* wr = att_m1_w + lane * D2;
        const float* ob = sc_out + g * 128;
#pragma unroll 2
        for (int d = 0; d < D2; d += 4) {
          const float4 w4 = *(const float4*)(wr + d);
          const float4 o4 = *(const float4*)&ob[d];
          m1 = fmaf(w4.x, o4.x, fmaf(w4.y, o4.y, fmaf(w4.z, o4.z, fmaf(w4.w, o4.w, m1))));
        }
      }
      sc_m1[g * 64 + lane] = fmaxf(m1, 0.f);

      // h = att_m2 @ m1 + b
      float hv = att_m2_b[lane];
      {
        const float* wr = att_m2_w + lane * HID;
        const float* mb = sc_m1 + g * 64;
#pragma unroll 2
        for (int d = 0; d < HID; d += 4) {
          const float4 w4 = *(const float4*)(wr + d);
          const float4 m4 = *(const float4*)&mb[d];
          hv = fmaf(w4.x, m4.x, fmaf(w4.y, m4.y, fmaf(w4.z, m4.z, fmaf(w4.w, m4.w, hv))));
        }
      }
      // x = concat(h, one_hot(cat,12))
      sc_x[g * 80 + lane] = hv;
      if (lane < 12) {
        const int cat = cat_feat[bw];
        sc_x[g * 80 + 64 + lane] = (cat == lane) ? 1.f : 0.f;
      }

      // h1 = relu(mlp_w1 @ x + b1) : 76 outputs
      const float* xb = sc_x + g * 80;
      {
        float h1a = mlp_b1[lane];
        const float* wr = mlp_w1 + lane * MLPD;
#pragma unroll 2
        for (int k = 0; k < MLPD; k += 4) {
          const float4 w4 = *(const float4*)(wr + k);
          const float4 x4 = *(const float4*)&xb[k];
          h1a = fmaf(w4.x, x4.x, fmaf(w4.y, x4.y, fmaf(w4.z, x4.z, fmaf(w4.w, x4.w, h1a))));
        }
        sc_h1[g * 80 + lane] = fmaxf(h1a, 0.f);
        if (lane < 12) {
          float h1b = mlp_b1[64 + lane];
          const float* wr2 = mlp_w1 + (64 + lane) * MLPD;
#pragma unroll 2
          for (int k = 0; k < MLPD; k += 4) {
            const float4 w4 = *(const float4*)(wr2 + k);
            const float4 x4 = *(const float4*)&xb[k];
            h1b = fmaf(w4.x, x4.x, fmaf(w4.y, x4.y, fmaf(w4.z, x4.z, fmaf(w4.w, x4.w, h1b))));
          }
          sc_h1[g * 80 + 64 + lane] = fmaxf(h1b, 0.f);
        }
      }

      // h2 = relu(mlp_w2 @ h1 + b2) ; z = mlp_w3 @ h2 + b3 ; sigmoid
      float h2 = mlp_b2[lane];
      {
        const float* wr = mlp_w2 + lane * MLPD;
        const float* hb = sc_h1 + g * 80;
#pragma unroll 2
        for (int k = 0; k < MLPD; k += 4) {
          const float4 w4 = *(const float4*)(wr + k);
          const float4 h4 = *(const float4*)&hb[k];
          h2 = fmaf(w4.x, h4.x, fmaf(w4.y, h4.y, fmaf(w4.z, h4.z, fmaf(w4.w, h4.w, h2))));
        }
      }
      h2 = fmaxf(h2, 0.f);
      float zz = mlp_w3[lane] * h2;
#pragma unroll
      for (int off = 32; off >= 1; off >>= 1) zz += __shfl_xor(zz, off, 64);
      if (lane == 0) out[bw] = 1.f / (1.f + __expf(-(zz + mlp_b3[0])));
    }
  }
}

extern "C" void kernel_launch(void* const* d_in, const int* in_sizes, int n_in,
                              void* d_out, int out_size, void* d_ws, size_t ws_size,
                              hipStream_t stream) {
  short* ws = (short*)d_ws;
  prep_weights<<<(NFRAG * 64 + 255) / 256, 256, 0, stream>>>(
      (const float*)d_in[10],  // lin_event_w
      (const float*)d_in[12],  // gcn_w1
      (const float*)d_in[14],  // gcn_w2
      (const float*)d_in[16],  // att_w1_w
      (const float*)d_in[18],  // att_w2_w
      ws);
  tempme_fused<<<NBLK, NT, 0, stream>>>(
      (const int*)d_in[0],    // node_idx
      (const int*)d_in[1],    // edge_idx
      (const int*)d_in[2],    // cat_feat
      (const float*)d_in[3],  // t_records
      (const float*)d_in[4],  // edge_identify
      // d_in[5] cut_time_l unused by reference
      (const float*)d_in[6],  // node_embed
      (const float*)d_in[7],  // edge_embed
      (const float*)d_in[8],  // basis_freq
      (const float*)d_in[9],  // phase
      (const float*)d_in[11],                          // lin_event_b
      (const float*)d_in[13],                          // gcn_b1
      (const float*)d_in[15],                          // gcn_b2
      (const float*)d_in[17],                          // att_w1_b
      (const float*)d_in[19],                          // att_w2_b
      (const float*)d_in[20], (const float*)d_in[21],  // att_m1
      (const float*)d_in[22], (const float*)d_in[23],  // att_m2
      (const float*)d_in[24], (const float*)d_in[25],  // mlp1
      (const float*)d_in[26], (const float*)d_in[27],  // mlp2
      (const float*)d_in[28], (const float*)d_in[29],  // mlp3
      ws,
      (float*)d_out);
}